// Round 1
// baseline (155.876 us; speedup 1.0000x reference)
//
#include <hip/hip_runtime.h>
#include <math.h>

#define C 32
#define OUT_DIM 288

__device__ __forceinline__ float gelu_tanh(float x) {
    // jax.nn.gelu approximate=True
    float x3 = x * x * x;
    float t = tanhf(0.7978845608028654f * (x + 0.044715f * x3));
    return 0.5f * x * (1.0f + t);
}

__global__ void hist_kernel(const int* __restrict__ recv, int E, int* __restrict__ counts) {
    int e = blockIdx.x * 256 + threadIdx.x;
    if (e < E) atomicAdd(&counts[recv[e]], 1);
}

// Single-block chunked Hillis-Steele scan: offsets[i+1] = inclusive prefix, cursor[i] = exclusive prefix
__global__ void scan_kernel(const int* __restrict__ counts, int* __restrict__ offsets,
                            int* __restrict__ cursor, int n) {
    __shared__ int buf[256];
    __shared__ int carry_s;
    const int t = threadIdx.x;
    if (t == 0) { carry_s = 0; offsets[0] = 0; }
    __syncthreads();
    for (int base = 0; base < n; base += 256) {
        int i = base + t;
        int v = (i < n) ? counts[i] : 0;
        buf[t] = v;
        __syncthreads();
        int sum = v;
        for (int off = 1; off < 256; off <<= 1) {
            int add = (t >= off) ? buf[t - off] : 0;
            __syncthreads();
            sum += add;
            buf[t] = sum;
            __syncthreads();
        }
        int inc = sum + carry_s;
        if (i < n) { offsets[i + 1] = inc; cursor[i] = inc - v; }
        __syncthreads();
        if (t == 255) carry_s = inc;
        __syncthreads();
    }
}

__global__ void scatter_kernel(const int* __restrict__ recv, int E,
                               int* __restrict__ cursor, int* __restrict__ edge_ids) {
    int e = blockIdx.x * 256 + threadIdx.x;
    if (e < E) {
        int p = atomicAdd(&cursor[recv[e]], 1);
        edge_ids[p] = e;
    }
}

// One 32-lane group per node (lane = channel). 8 nodes per 256-thread block.
// Stage layout per node (26 arrays of 32 floats):
//  0: a0a (x0 sum)   1: a0b (tp0 sum)
//  2..4:  a1a[i] (x1 sum)    5..7:  a1b[i] (tp1 sum)
//  8..12: a2[m]
//  13: h0   14..16: h1[i]   17..21: h2[m]
//  22: x0n (node's own 0e)  23..25: x1n[i]
__global__ __launch_bounds__(256) void agg_node_kernel(
    const float* __restrict__ node0, const float* __restrict__ node1,
    const float* __restrict__ pos,
    const int* __restrict__ senders, const int* __restrict__ offsets,
    const int* __restrict__ edge_ids,
    const float* __restrict__ Wpre0, const float* __restrict__ Wpre1,
    const float* __restrict__ Wpre2,
    const float* __restrict__ Wpost0, const float* __restrict__ Wpost1,
    const float* __restrict__ Wpost2,
    const float* __restrict__ Wsc0, const float* __restrict__ Wsc1,
    float* __restrict__ out, int N)
{
    __shared__ float st[8][26][32];
    const int lane = threadIdx.x & 31;   // channel index c
    const int grp  = threadIdx.x >> 5;   // node slot within block
    const int node = blockIdx.x * 8 + grp;
    const bool valid = (node < N);

    const float S2 = 0.70710678118654752f;   // 1/sqrt(2)
    const float S6 = 0.40824829046386302f;   // 1/sqrt(6)
    const float SQRT3 = 1.7320508075688772f;
    const float INV_SQRT3 = 0.57735026918962576f;
    const float INV_DEN = 1.0f / 16.0f;

    float ax0 = 0.f, atp0 = 0.f;
    float ax1x = 0.f, ax1y = 0.f, ax1z = 0.f;
    float at1x = 0.f, at1y = 0.f, at1z = 0.f;
    float a2v0 = 0.f, a2v1 = 0.f, a2v2 = 0.f, a2v3 = 0.f, a2v4 = 0.f;

    if (valid) {
        const float px = pos[node * 3 + 0];
        const float py = pos[node * 3 + 1];
        const float pz = pos[node * 3 + 2];
        const int beg = offsets[node];
        const int end = offsets[node + 1];
        for (int k = beg; k < end; ++k) {
            const int e = edge_ids[k];
            const int s = senders[e];
            const float rx = px - pos[s * 3 + 0];
            const float ry = py - pos[s * 3 + 1];
            const float rz = pz - pos[s * 3 + 2];
            const float nrm = sqrtf(rx * rx + ry * ry + rz * rz);
            const float f = SQRT3 / fmaxf(nrm, 1e-9f);
            const float shx = rx * f, shy = ry * f, shz = rz * f;

            const float x0 = node0[s * C + lane];
            const int b1 = (s * C + lane) * 3;
            const float x1x = node1[b1 + 0];
            const float x1y = node1[b1 + 1];
            const float x1z = node1[b1 + 2];

            ax0 += x0;
            atp0 += x1x * shx + x1y * shy + x1z * shz;
            ax1x += x1x; ax1y += x1y; ax1z += x1z;
            at1x += x0 * shx; at1y += x0 * shy; at1z += x0 * shz;
            a2v0 += S2 * (x1x * shy + x1y * shx);
            a2v1 += S2 * (x1y * shz + x1z * shy);
            a2v2 += S6 * (2.f * x1z * shz - x1x * shx - x1y * shy);
            a2v3 += S2 * (x1x * shz + x1z * shx);
            a2v4 += S2 * (x1x * shx - x1y * shy);
        }
    }

    // stage aggregates (scaled by 1/DEN) + node's own features
    st[grp][0][lane] = ax0 * INV_DEN;
    st[grp][1][lane] = atp0 * (INV_DEN * INV_SQRT3);
    st[grp][2][lane] = ax1x * INV_DEN;
    st[grp][3][lane] = ax1y * INV_DEN;
    st[grp][4][lane] = ax1z * INV_DEN;
    st[grp][5][lane] = at1x * INV_DEN;
    st[grp][6][lane] = at1y * INV_DEN;
    st[grp][7][lane] = at1z * INV_DEN;
    st[grp][8][lane]  = a2v0 * INV_DEN;
    st[grp][9][lane]  = a2v1 * INV_DEN;
    st[grp][10][lane] = a2v2 * INV_DEN;
    st[grp][11][lane] = a2v3 * INV_DEN;
    st[grp][12][lane] = a2v4 * INV_DEN;
    {
        float x0n = 0.f, x1nx = 0.f, x1ny = 0.f, x1nz = 0.f;
        if (valid) {
            x0n = node0[node * C + lane];
            const int b = (node * C + lane) * 3;
            x1nx = node1[b + 0]; x1ny = node1[b + 1]; x1nz = node1[b + 2];
        }
        st[grp][22][lane] = x0n;
        st[grp][23][lane] = x1nx;
        st[grp][24][lane] = x1ny;
        st[grp][25][lane] = x1nz;
    }
    __syncthreads();

    // h = pre-linear (+gelu on 0e). lane = output channel d.
    const int d = lane;
    float h0p = 0.f;
    float h1x = 0.f, h1y = 0.f, h1z = 0.f;
    float h2v0 = 0.f, h2v1 = 0.f, h2v2 = 0.f, h2v3 = 0.f, h2v4 = 0.f;
#pragma unroll 8
    for (int c = 0; c < C; ++c) {
        const float wa0 = Wpre0[c * C + d];
        const float wb0 = Wpre0[(C + c) * C + d];
        h0p += st[grp][0][c] * wa0 + st[grp][1][c] * wb0;
        const float wa1 = Wpre1[c * C + d];
        const float wb1 = Wpre1[(C + c) * C + d];
        h1x += st[grp][2][c] * wa1 + st[grp][5][c] * wb1;
        h1y += st[grp][3][c] * wa1 + st[grp][6][c] * wb1;
        h1z += st[grp][4][c] * wa1 + st[grp][7][c] * wb1;
        const float w2 = Wpre2[c * C + d];
        h2v0 += st[grp][8][c] * w2;
        h2v1 += st[grp][9][c] * w2;
        h2v2 += st[grp][10][c] * w2;
        h2v3 += st[grp][11][c] * w2;
        h2v4 += st[grp][12][c] * w2;
    }
    const float h0 = gelu_tanh(h0p);
    __syncthreads();  // (writes go to disjoint arrays, but keep ordering clean)
    st[grp][13][d] = h0;
    st[grp][14][d] = h1x; st[grp][15][d] = h1y; st[grp][16][d] = h1z;
    st[grp][17][d] = h2v0; st[grp][18][d] = h2v1; st[grp][19][d] = h2v2;
    st[grp][20][d] = h2v3; st[grp][21][d] = h2v4;
    __syncthreads();

    // o = post-linear + shortcut
    float o0 = 0.f;
    float o1x = 0.f, o1y = 0.f, o1z = 0.f;
    float o2v0 = 0.f, o2v1 = 0.f, o2v2 = 0.f, o2v3 = 0.f, o2v4 = 0.f;
#pragma unroll 8
    for (int c = 0; c < C; ++c) {
        const float wp0 = Wpost0[c * C + d];
        const float ws0 = Wsc0[c * C + d];
        o0 += st[grp][13][c] * wp0 + st[grp][22][c] * ws0;
        const float wp1 = Wpost1[c * C + d];
        const float ws1 = Wsc1[c * C + d];
        o1x += st[grp][14][c] * wp1 + st[grp][23][c] * ws1;
        o1y += st[grp][15][c] * wp1 + st[grp][24][c] * ws1;
        o1z += st[grp][16][c] * wp1 + st[grp][25][c] * ws1;
        const float wp2 = Wpost2[c * C + d];
        o2v0 += st[grp][17][c] * wp2;
        o2v1 += st[grp][18][c] * wp2;
        o2v2 += st[grp][19][c] * wp2;
        o2v3 += st[grp][20][c] * wp2;
        o2v4 += st[grp][21][c] * wp2;
    }

    if (valid) {
        float* po = out + (size_t)node * OUT_DIM;
        po[d] = o0;
        po[32 + d * 3 + 0] = o1x;
        po[32 + d * 3 + 1] = o1y;
        po[32 + d * 3 + 2] = o1z;
        po[128 + d * 5 + 0] = o2v0;
        po[128 + d * 5 + 1] = o2v1;
        po[128 + d * 5 + 2] = o2v2;
        po[128 + d * 5 + 3] = o2v3;
        po[128 + d * 5 + 4] = o2v4;
    }
}

extern "C" void kernel_launch(void* const* d_in, const int* in_sizes, int n_in,
                              void* d_out, int out_size, void* d_ws, size_t ws_size,
                              hipStream_t stream) {
    const float* node0   = (const float*)d_in[0];
    const float* node1   = (const float*)d_in[1];
    const float* pos     = (const float*)d_in[2];
    const int*   senders = (const int*)d_in[3];
    const int*   recv    = (const int*)d_in[4];
    const float* Wpre0   = (const float*)d_in[5];
    const float* Wpre1   = (const float*)d_in[6];
    const float* Wpre2   = (const float*)d_in[7];
    const float* Wpost0  = (const float*)d_in[8];
    const float* Wpost1  = (const float*)d_in[9];
    const float* Wpost2  = (const float*)d_in[10];
    const float* Wsc0    = (const float*)d_in[11];
    const float* Wsc1    = (const float*)d_in[12];
    float* out = (float*)d_out;

    const int N = in_sizes[2] / 3;
    const int E = in_sizes[3];

    int* counts   = (int*)d_ws;
    int* offsets  = counts + N;
    int* cursor   = offsets + (N + 1);
    int* edge_ids = cursor + N;

    hipMemsetAsync(counts, 0, (size_t)N * sizeof(int), stream);
    hist_kernel<<<(E + 255) / 256, 256, 0, stream>>>(recv, E, counts);
    scan_kernel<<<1, 256, 0, stream>>>(counts, offsets, cursor, N);
    scatter_kernel<<<(E + 255) / 256, 256, 0, stream>>>(recv, E, cursor, edge_ids);
    agg_node_kernel<<<(N + 7) / 8, 256, 0, stream>>>(
        node0, node1, pos, senders, offsets, edge_ids,
        Wpre0, Wpre1, Wpre2, Wpost0, Wpost1, Wpost2, Wsc0, Wsc1,
        out, N);
}

// Round 2
// 105.480 us; speedup vs baseline: 1.4778x; 1.4778x over previous
//
#include <hip/hip_runtime.h>
#include <math.h>

#define C 32
#define OUT_DIM 288

__device__ __forceinline__ float gelu_tanh(float x) {
    // jax.nn.gelu approximate=True
    float x3 = x * x * x;
    float t = tanhf(0.7978845608028654f * (x + 0.044715f * x3));
    return 0.5f * x * (1.0f + t);
}

__global__ void hist_kernel(const int* __restrict__ recv, int E, int* __restrict__ counts) {
    int e = blockIdx.x * 256 + threadIdx.x;
    if (e < E) atomicAdd(&counts[recv[e]], 1);
}

// One-block scan, 1024 threads, ~10 elems/thread:
// offsets[i+1] = inclusive prefix, cursor[i] = exclusive prefix, offsets[0]=0
__global__ __launch_bounds__(1024) void scan_kernel(
    const int* __restrict__ counts, int* __restrict__ offsets,
    int* __restrict__ cursor, int n)
{
    __shared__ int wbase[17];
    const int tid = threadIdx.x;
    const int lane = tid & 63;
    const int wid = tid >> 6;
    const int chunk = (n + 1023) >> 10;
    const int base = tid * chunk;

    int sum = 0;
    for (int i = 0; i < chunk; ++i) {
        int idx = base + i;
        if (idx < n) sum += counts[idx];
    }
    // inclusive wave scan of per-thread sums
    int v = sum;
    for (int off = 1; off < 64; off <<= 1) {
        int u = __shfl_up(v, off, 64);
        if (lane >= off) v += u;
    }
    __shared__ int wtot[16];
    if (lane == 63) wtot[wid] = v;
    __syncthreads();
    if (tid == 0) {
        int acc = 0;
        for (int w2 = 0; w2 < 16; ++w2) { wbase[w2] = acc; acc += wtot[w2]; }
    }
    __syncthreads();
    int run = wbase[wid] + (v - sum);  // exclusive prefix for this thread's chunk
    for (int i = 0; i < chunk; ++i) {
        int idx = base + i;
        if (idx < n) {
            int cv = counts[idx];
            cursor[idx] = run;
            run += cv;
            offsets[idx + 1] = run;
        }
    }
    if (tid == 0) offsets[0] = 0;
}

__global__ void scatter_kernel(const int* __restrict__ recv, int E,
                               int* __restrict__ cursor, int* __restrict__ edge_ids) {
    int e = blockIdx.x * 256 + threadIdx.x;
    if (e < E) {
        int p = atomicAdd(&cursor[recv[e]], 1);
        edge_ids[p] = e;
    }
}

// One wave (64 lanes) per node. lane = half*32 + c (c = channel).
// Halves process interleaved edges (2x parallelism) with a 2-edge unroll each
// -> 4 dependent load chains in flight. Cross-half combine via shfl_xor(32).
// LDS stage layout per wave (26 arrays of 32 floats):
//  0: a0a  1: a0b  2..4: a1a[i]  5..7: a1b[i]  8..12: a2[m]
//  13: h0  14..16: h1[i]  17..21: h2[m]  22: x0n  23..25: x1n[i]
__global__ __launch_bounds__(256) void agg_node_kernel(
    const float* __restrict__ node0, const float* __restrict__ node1,
    const float* __restrict__ pos,
    const int* __restrict__ senders, const int* __restrict__ offsets,
    const int* __restrict__ edge_ids,
    const float* __restrict__ Wpre0, const float* __restrict__ Wpre1,
    const float* __restrict__ Wpre2,
    const float* __restrict__ Wpost0, const float* __restrict__ Wpost1,
    const float* __restrict__ Wpost2,
    const float* __restrict__ Wsc0, const float* __restrict__ Wsc1,
    float* __restrict__ out, int N)
{
    __shared__ float st[4][26][32];
    const int tid  = threadIdx.x;
    const int w    = tid >> 6;      // wave in block
    const int lane = tid & 63;
    const int half = lane >> 5;
    const int c    = lane & 31;     // channel
    const int node = blockIdx.x * 4 + w;
    const bool valid = (node < N);

    const float S2 = 0.70710678118654752f;   // 1/sqrt(2)
    const float S6 = 0.40824829046386302f;   // 1/sqrt(6)
    const float SQRT3 = 1.7320508075688772f;
    const float INV_SQRT3 = 0.57735026918962576f;
    const float INV_DEN = 1.0f / 16.0f;

    float ax0 = 0.f, atp0 = 0.f;
    float ax1x = 0.f, ax1y = 0.f, ax1z = 0.f;
    float at1x = 0.f, at1y = 0.f, at1z = 0.f;
    float a2v0 = 0.f, a2v1 = 0.f, a2v2 = 0.f, a2v3 = 0.f, a2v4 = 0.f;

#define EDGE_ACCUM(S)                                                       \
    {                                                                       \
        const int s_ = (S);                                                 \
        const float rx = px - pos[s_ * 3 + 0];                              \
        const float ry = py - pos[s_ * 3 + 1];                              \
        const float rz = pz - pos[s_ * 3 + 2];                              \
        const float nrm = sqrtf(rx * rx + ry * ry + rz * rz);               \
        const float f = SQRT3 / fmaxf(nrm, 1e-9f);                          \
        const float shx = rx * f, shy = ry * f, shz = rz * f;               \
        const float x0 = node0[s_ * C + c];                                 \
        const int b1 = (s_ * C + c) * 3;                                    \
        const float x1x = node1[b1 + 0];                                    \
        const float x1y = node1[b1 + 1];                                    \
        const float x1z = node1[b1 + 2];                                    \
        ax0 += x0;                                                          \
        atp0 += x1x * shx + x1y * shy + x1z * shz;                          \
        ax1x += x1x; ax1y += x1y; ax1z += x1z;                              \
        at1x += x0 * shx; at1y += x0 * shy; at1z += x0 * shz;               \
        a2v0 += S2 * (x1x * shy + x1y * shx);                               \
        a2v1 += S2 * (x1y * shz + x1z * shy);                               \
        a2v2 += S6 * (2.f * x1z * shz - x1x * shx - x1y * shy);             \
        a2v3 += S2 * (x1x * shz + x1z * shx);                               \
        a2v4 += S2 * (x1x * shx - x1y * shy);                               \
    }

    if (valid) {
        const float px = pos[node * 3 + 0];
        const float py = pos[node * 3 + 1];
        const float pz = pos[node * 3 + 2];
        const int end = offsets[node + 1];
        int k = offsets[node] + half;   // this half's edges: k, k+2, k+4, ...
        while (k + 2 < end) {
            // fetch both edges' indirection first (2 chains in flight)
            const int e0 = edge_ids[k];
            const int e1 = edge_ids[k + 2];
            const int s0 = senders[e0];
            const int s1 = senders[e1];
            EDGE_ACCUM(s0);
            EDGE_ACCUM(s1);
            k += 4;
        }
        if (k < end) {
            const int e0 = edge_ids[k];
            const int s0 = senders[e0];
            EDGE_ACCUM(s0);
        }
    }
#undef EDGE_ACCUM

    // combine halves (both halves end up holding the totals)
    ax0  += __shfl_xor(ax0, 32, 64);
    atp0 += __shfl_xor(atp0, 32, 64);
    ax1x += __shfl_xor(ax1x, 32, 64);
    ax1y += __shfl_xor(ax1y, 32, 64);
    ax1z += __shfl_xor(ax1z, 32, 64);
    at1x += __shfl_xor(at1x, 32, 64);
    at1y += __shfl_xor(at1y, 32, 64);
    at1z += __shfl_xor(at1z, 32, 64);
    a2v0 += __shfl_xor(a2v0, 32, 64);
    a2v1 += __shfl_xor(a2v1, 32, 64);
    a2v2 += __shfl_xor(a2v2, 32, 64);
    a2v3 += __shfl_xor(a2v3, 32, 64);
    a2v4 += __shfl_xor(a2v4, 32, 64);

    if (half == 0) {
        st[w][0][c] = ax0 * INV_DEN;
        st[w][1][c] = atp0 * (INV_DEN * INV_SQRT3);
        st[w][2][c] = ax1x * INV_DEN;
        st[w][3][c] = ax1y * INV_DEN;
        st[w][4][c] = ax1z * INV_DEN;
        st[w][5][c] = at1x * INV_DEN;
        st[w][6][c] = at1y * INV_DEN;
        st[w][7][c] = at1z * INV_DEN;
        st[w][8][c]  = a2v0 * INV_DEN;
        st[w][9][c]  = a2v1 * INV_DEN;
        st[w][10][c] = a2v2 * INV_DEN;
        st[w][11][c] = a2v3 * INV_DEN;
        st[w][12][c] = a2v4 * INV_DEN;
    } else {
        float x0n = 0.f, x1nx = 0.f, x1ny = 0.f, x1nz = 0.f;
        if (valid) {
            x0n = node0[node * C + c];
            const int b = (node * C + c) * 3;
            x1nx = node1[b + 0]; x1ny = node1[b + 1]; x1nz = node1[b + 2];
        }
        st[w][22][c] = x0n;
        st[w][23][c] = x1nx;
        st[w][24][c] = x1ny;
        st[w][25][c] = x1nz;
    }
    __syncthreads();

    // pre-linear: half0 -> h0 (gelu), h1; half1 -> h2
    const int d = c;
    if (half == 0) {
        float h0p = 0.f, h1x = 0.f, h1y = 0.f, h1z = 0.f;
#pragma unroll 8
        for (int c2 = 0; c2 < C; ++c2) {
            const float wa0 = Wpre0[c2 * C + d];
            const float wb0 = Wpre0[(C + c2) * C + d];
            h0p += st[w][0][c2] * wa0 + st[w][1][c2] * wb0;
            const float wa1 = Wpre1[c2 * C + d];
            const float wb1 = Wpre1[(C + c2) * C + d];
            h1x += st[w][2][c2] * wa1 + st[w][5][c2] * wb1;
            h1y += st[w][3][c2] * wa1 + st[w][6][c2] * wb1;
            h1z += st[w][4][c2] * wa1 + st[w][7][c2] * wb1;
        }
        const float h0 = gelu_tanh(h0p);
        st[w][13][d] = h0;
        st[w][14][d] = h1x; st[w][15][d] = h1y; st[w][16][d] = h1z;
    } else {
        float h2v0 = 0.f, h2v1 = 0.f, h2v2 = 0.f, h2v3 = 0.f, h2v4 = 0.f;
#pragma unroll 8
        for (int c2 = 0; c2 < C; ++c2) {
            const float w2 = Wpre2[c2 * C + d];
            h2v0 += st[w][8][c2] * w2;
            h2v1 += st[w][9][c2] * w2;
            h2v2 += st[w][10][c2] * w2;
            h2v3 += st[w][11][c2] * w2;
            h2v4 += st[w][12][c2] * w2;
        }
        st[w][17][d] = h2v0; st[w][18][d] = h2v1; st[w][19][d] = h2v2;
        st[w][20][d] = h2v3; st[w][21][d] = h2v4;
    }
    __syncthreads();

    // post-linear + shortcut: half0 -> o0, o1; half1 -> o2
    if (half == 0) {
        float o0 = 0.f, o1x = 0.f, o1y = 0.f, o1z = 0.f;
#pragma unroll 8
        for (int c2 = 0; c2 < C; ++c2) {
            const float wp0 = Wpost0[c2 * C + d];
            const float ws0 = Wsc0[c2 * C + d];
            o0 += st[w][13][c2] * wp0 + st[w][22][c2] * ws0;
            const float wp1 = Wpost1[c2 * C + d];
            const float ws1 = Wsc1[c2 * C + d];
            o1x += st[w][14][c2] * wp1 + st[w][23][c2] * ws1;
            o1y += st[w][15][c2] * wp1 + st[w][24][c2] * ws1;
            o1z += st[w][16][c2] * wp1 + st[w][25][c2] * ws1;
        }
        if (valid) {
            float* po = out + (size_t)node * OUT_DIM;
            po[d] = o0;
            po[32 + d * 3 + 0] = o1x;
            po[32 + d * 3 + 1] = o1y;
            po[32 + d * 3 + 2] = o1z;
        }
    } else {
        float o2v0 = 0.f, o2v1 = 0.f, o2v2 = 0.f, o2v3 = 0.f, o2v4 = 0.f;
#pragma unroll 8
        for (int c2 = 0; c2 < C; ++c2) {
            const float wp2 = Wpost2[c2 * C + d];
            o2v0 += st[w][17][c2] * wp2;
            o2v1 += st[w][18][c2] * wp2;
            o2v2 += st[w][19][c2] * wp2;
            o2v3 += st[w][20][c2] * wp2;
            o2v4 += st[w][21][c2] * wp2;
        }
        if (valid) {
            float* po = out + (size_t)node * OUT_DIM;
            po[128 + d * 5 + 0] = o2v0;
            po[128 + d * 5 + 1] = o2v1;
            po[128 + d * 5 + 2] = o2v2;
            po[128 + d * 5 + 3] = o2v3;
            po[128 + d * 5 + 4] = o2v4;
        }
    }
}

extern "C" void kernel_launch(void* const* d_in, const int* in_sizes, int n_in,
                              void* d_out, int out_size, void* d_ws, size_t ws_size,
                              hipStream_t stream) {
    const float* node0   = (const float*)d_in[0];
    const float* node1   = (const float*)d_in[1];
    const float* pos     = (const float*)d_in[2];
    const int*   senders = (const int*)d_in[3];
    const int*   recv    = (const int*)d_in[4];
    const float* Wpre0   = (const float*)d_in[5];
    const float* Wpre1   = (const float*)d_in[6];
    const float* Wpre2   = (const float*)d_in[7];
    const float* Wpost0  = (const float*)d_in[8];
    const float* Wpost1  = (const float*)d_in[9];
    const float* Wpost2  = (const float*)d_in[10];
    const float* Wsc0    = (const float*)d_in[11];
    const float* Wsc1    = (const float*)d_in[12];
    float* out = (float*)d_out;

    const int N = in_sizes[2] / 3;
    const int E = in_sizes[3];

    int* counts   = (int*)d_ws;
    int* offsets  = counts + N;
    int* cursor   = offsets + (N + 1);
    int* edge_ids = cursor + N;

    hipMemsetAsync(counts, 0, (size_t)N * sizeof(int), stream);
    hist_kernel<<<(E + 255) / 256, 256, 0, stream>>>(recv, E, counts);
    scan_kernel<<<1, 1024, 0, stream>>>(counts, offsets, cursor, N);
    scatter_kernel<<<(E + 255) / 256, 256, 0, stream>>>(recv, E, cursor, edge_ids);
    agg_node_kernel<<<(N + 3) / 4, 256, 0, stream>>>(
        node0, node1, pos, senders, offsets, edge_ids,
        Wpre0, Wpre1, Wpre2, Wpost0, Wpost1, Wpost2, Wsc0, Wsc1,
        out, N);
}